// Round 7
// baseline (180.070 us; speedup 1.0000x reference)
//
#include <hip/hip_runtime.h>

#define N_TOK 576          // 24*24 patches per image
#define HP    24
#define PS    16
#define IMG   384
#define ATTN_SCALE 0.35355339059327373f   // 8^-0.5
#define NBLK  288          // grid size; 4 tokens/block; must match launch
#define BAR_STRIDE 132     // per-barrier ctl: 8 grp ctrs @16-uint spacing,
                           // root @128, flag @129

// ---- agent-coherent (LLC-direct) data path --------------------------------
// Cross-block data moves via agent-scope relaxed atomics (sc-bit ops that
// bypass L1/L2, served at the device-coherent LLC). No cache-maintenance
// fences anywhere (round-5's 53us/barrier cost). Validated in round 6.
__device__ __forceinline__ void stg_u32(float* p, float v) {
    union { float f; unsigned u; } c; c.f = v;
    __hip_atomic_store((unsigned*)p, c.u, __ATOMIC_RELAXED,
                       __HIP_MEMORY_SCOPE_AGENT);
}
__device__ __forceinline__ float2 ldg_f2(const float* p) {
    unsigned long long u = __hip_atomic_load(
        (const unsigned long long*)p, __ATOMIC_RELAXED,
        __HIP_MEMORY_SCOPE_AGENT);
    union { unsigned long long u; float2 f; } c; c.u = u; return c.f;
}

// ---- fence-free tree barrier ----------------------------------------------
// Visibility: __syncthreads() drains each wave's vmem (s_waitcnt vmcnt(0)
// before s_barrier); our data stores are LLC-acked, so arrival => LLC-visible.
// Readers are LLC-direct, so no acquire-invalidate needed. 8 group counters
// on separate 64B lines (36 arrivals each), then a root, then a flag.
// Deadlock-safe: 288 blocks, 43.3KB LDS (3/CU fits), __launch_bounds__(256,2)
// -> >=2 blocks/CU resident = 512 >= 288.
__device__ __forceinline__ void gbar(unsigned* base)
{
    __syncthreads();
    if (threadIdx.x == 0) {
        unsigned* grp  = base + (blockIdx.x & 7) * 16;
        unsigned* root = base + 128;
        unsigned* flag = base + 129;
        const unsigned old = __hip_atomic_fetch_add(
            grp, 1u, __ATOMIC_RELAXED, __HIP_MEMORY_SCOPE_AGENT);
        if (old == (NBLK/8) - 1u) {
            const unsigned r = __hip_atomic_fetch_add(
                root, 1u, __ATOMIC_RELAXED, __HIP_MEMORY_SCOPE_AGENT);
            if (r == 7u)
                __hip_atomic_store(flag, 1u, __ATOMIC_RELAXED,
                                   __HIP_MEMORY_SCOPE_AGENT);
        }
        while (!__hip_atomic_load(flag, __ATOMIC_RELAXED,
                                  __HIP_MEMORY_SCOPE_AGENT))
            __builtin_amdgcn_s_sleep(2);
    }
    __syncthreads();
}

// One fused kernel: 288 blocks x 256 threads; wave w owns token blk*4+w.
// K/V staged into LDS once per block (transposed [16][578]) -> phases 2/3
// read LDS, not the LLC. This is the round-6 -> round-7 fix: LLC atomic
// transactions drop from 10.6M to 2.65M device-wide.
__global__ __launch_bounds__(256, 2) void k_all(
    const float* __restrict__ x,
    const float* __restrict__ Wq, const float* __restrict__ bq,
    const float* __restrict__ Wk, const float* __restrict__ bk,
    const float* __restrict__ Wv, const float* __restrict__ bv,
    const float* __restrict__ Wsq, const float* __restrict__ bsq,
    const float* __restrict__ Wsk, const float* __restrict__ bsk,
    const float* __restrict__ Wsv, const float* __restrict__ bsv,
    const float* __restrict__ ln_g, const float* __restrict__ ln_b,
    const float* __restrict__ Wp,   const float* __restrict__ bp,
    float* __restrict__ k1, float* __restrict__ v1,
    float* __restrict__ k2, float* __restrict__ v2,
    unsigned* __restrict__ ctl,     // 3*BAR_STRIDE barrier words + smax
    float* __restrict__ out)
{
    __shared__ float kv[16][578];     // K rows 0..7, V rows 8..15 (transposed)
    __shared__ float tile[32*40];     // bilateral tile, stride 40
    __shared__ float spt[17*17];      // spatial weight table
    __shared__ float s_sig[4][3];
    __shared__ int   s_half;

    const int t = threadIdx.x, lane = t & 63, w = t >> 6;
    const int blk = blockIdx.x;
    const int tok = blk*4 + w;                 // 0..1151
    const int b   = tok / N_TOK;
    unsigned* smax = ctl + 3*BAR_STRIDE;

    // ---------------- Phase 1: patchify + QKV1 (all 4 waves) --------------
    float qv[8];                               // q1 row, kept in registers
    {
        const int n  = tok % N_TOK;
        const int py = n / HP, px = n % HP;
        const int iy = lane >> 2, ix0 = (lane & 3) * 4;
        const float4 pv = *(const float4*)
            &x[b*IMG*IMG + (py*PS + iy)*IMG + px*PS + ix0];

        float acc[24];
#pragma unroll
        for (int j = 0; j < 24; ++j) acc[j] = 0.f;
#pragma unroll
        for (int j = 0; j < 4; ++j) {
            const int ft = 4*lane + j;         // feature index / W row
            const float pvj = ((const float*)&pv)[j];
#pragma unroll
            for (int h = 0; h < 8; ++h) {
                acc[h]      += pvj * Wq[ft*8 + h];
                acc[8 + h]  += pvj * Wk[ft*8 + h];
                acc[16 + h] += pvj * Wv[ft*8 + h];
            }
        }
#pragma unroll
        for (int off = 32; off; off >>= 1)
#pragma unroll
            for (int j = 0; j < 24; ++j) acc[j] += __shfl_xor(acc[j], off);

#pragma unroll
        for (int h = 0; h < 8; ++h) qv[h] = acc[h] + bq[h];
        if (lane >= 8 && lane < 16)
            stg_u32(&k1[tok*8 + (lane & 7)], acc[8 + (lane & 7)]  + bk[lane & 7]);
        if (lane >= 16 && lane < 24)
            stg_u32(&v1[tok*8 + (lane & 7)], acc[16 + (lane & 7)] + bv[lane & 7]);
    }
    gbar(ctl + 0*BAR_STRIDE);

    // ---- stage K1/V1 (this image) into LDS: 4608 x 8B LLC loads / block --
    {
        const float* kb = k1 + b*N_TOK*8;
        const float* vb = v1 + b*N_TOK*8;
#pragma unroll
        for (int j = 0; j < 18; ++j) {
            const int e   = t + j*256;         // 0..4607
            const int src = (e >= 2304) ? 1 : 0;
            const int idx = src ? e - 2304 : e; // 0..2303
            const int r = idx >> 2, hp = idx & 3;
            const float2 d = ldg_f2((src ? vb : kb) + r*8 + hp*2);
            kv[src*8 + 2*hp + 0][r] = d.x;
            kv[src*8 + 2*hp + 1][r] = d.y;
        }
    }
    __syncthreads();

    // ---------------- Phase 2: attention 1 + QKV2 projection --------------
    float qv2[8];
    {
        float sc[9], mx = -1e30f;
#pragma unroll
        for (int ch = 0; ch < 9; ++ch) {
            const int r = ch*64 + lane;
            float d = 0.f;
#pragma unroll
            for (int h = 0; h < 8; ++h) d += qv[h]*kv[h][r];
            sc[ch] = d * ATTN_SCALE;
            mx = fmaxf(mx, sc[ch]);
        }
#pragma unroll
        for (int off = 32; off; off >>= 1) mx = fmaxf(mx, __shfl_xor(mx, off));

        float ssum = 0.f, o[8];
#pragma unroll
        for (int h = 0; h < 8; ++h) o[h] = 0.f;
#pragma unroll
        for (int ch = 0; ch < 9; ++ch) {
            const int r = ch*64 + lane;
            const float pw = __expf(sc[ch] - mx);
            ssum += pw;
#pragma unroll
            for (int h = 0; h < 8; ++h) o[h] += pw*kv[8 + h][r];
        }
#pragma unroll
        for (int off = 32; off; off >>= 1) {
            ssum += __shfl_xor(ssum, off);
#pragma unroll
            for (int h = 0; h < 8; ++h) o[h] += __shfl_xor(o[h], off);
        }
        const float inv = 1.f/ssum;
        float f[8];
#pragma unroll
        for (int h = 0; h < 8; ++h) f[h] = o[h]*inv;

        float sproj = 0.f;
        if (lane < 24) {
            const int mat = lane >> 3, h = lane & 7;
            const float* Wm = (mat==0)?Wsq:(mat==1)?Wsk:Wsv;
            const float* bm = (mat==0)?bsq:(mat==1)?bsk:bsv;
            float s = bm[h];
#pragma unroll
            for (int j = 0; j < 8; ++j) s += f[j]*Wm[j*8 + h];
            sproj = s;
            if (mat == 1) stg_u32(&k2[tok*8 + h], s);
            if (mat == 2) stg_u32(&v2[tok*8 + h], s);
        }
#pragma unroll
        for (int h = 0; h < 8; ++h) qv2[h] = __shfl(sproj, h);   // q2 in regs
    }
    gbar(ctl + 1*BAR_STRIDE);

    // ---- stage K2/V2 into LDS (overwrites; gbar's syncthreads = WAR ok) --
    {
        const float* kb = k2 + b*N_TOK*8;
        const float* vb = v2 + b*N_TOK*8;
#pragma unroll
        for (int j = 0; j < 18; ++j) {
            const int e   = t + j*256;
            const int src = (e >= 2304) ? 1 : 0;
            const int idx = src ? e - 2304 : e;
            const int r = idx >> 2, hp = idx & 3;
            const float2 d = ldg_f2((src ? vb : kb) + r*8 + hp*2);
            kv[src*8 + 2*hp + 0][r] = d.x;
            kv[src*8 + 2*hp + 1][r] = d.y;
        }
    }
    __syncthreads();

    // ---------------- Phase 3: attention 2 + LN + BoundedSoftplus ---------
    {
        float sc[9], mx = -1e30f;
#pragma unroll
        for (int ch = 0; ch < 9; ++ch) {
            const int r = ch*64 + lane;
            float d = 0.f;
#pragma unroll
            for (int h = 0; h < 8; ++h) d += qv2[h]*kv[h][r];
            sc[ch] = d * ATTN_SCALE;
            mx = fmaxf(mx, sc[ch]);
        }
#pragma unroll
        for (int off = 32; off; off >>= 1) mx = fmaxf(mx, __shfl_xor(mx, off));

        float ssum = 0.f, o[8];
#pragma unroll
        for (int h = 0; h < 8; ++h) o[h] = 0.f;
#pragma unroll
        for (int ch = 0; ch < 9; ++ch) {
            const int r = ch*64 + lane;
            const float pw = __expf(sc[ch] - mx);
            ssum += pw;
#pragma unroll
            for (int h = 0; h < 8; ++h) o[h] += pw*kv[8 + h][r];
        }
#pragma unroll
        for (int off = 32; off; off >>= 1) {
            ssum += __shfl_xor(ssum, off);
#pragma unroll
            for (int h = 0; h < 8; ++h) o[h] += __shfl_xor(o[h], off);
        }

        if (lane == 0) {
            const float inv = 1.f/ssum;
            float f[8];
            float mu = 0.f;
#pragma unroll
            for (int h = 0; h < 8; ++h) { f[h] = o[h]*inv; mu += f[h]; }
            mu *= 0.125f;
            float var = 0.f;
#pragma unroll
            for (int h = 0; h < 8; ++h) { const float d = f[h]-mu; var += d*d; }
            var *= 0.125f;
            const float rinv = rsqrtf(var + 1e-5f);
            float on[8];
#pragma unroll
            for (int h = 0; h < 8; ++h)
                on[h] = (f[h]-mu)*rinv*ln_g[h] + ln_b[h];
            float sv[3];
#pragma unroll
            for (int c = 0; c < 3; ++c) {
                float z = bp[c];
#pragma unroll
                for (int j = 0; j < 8; ++j) z += on[j]*Wp[j*3 + c];
                const float sp = (z > 20.f) ? z : log1pf(__expf(z));
                sv[c] = fminf(sp, 6.0f) + 1e-6f;
                s_sig[w][c] = sv[c];           // sigmas never leave the block
            }
            atomicMax((int*)smax, __float_as_int(fmaxf(sv[0], sv[1])));
        }
    }
    gbar(ctl + 2*BAR_STRIDE);

    // ---------------- Phase 4: half + bilateral for 4 patches -------------
    if (t == 0) {
        const int mi = __hip_atomic_load((const int*)smax, __ATOMIC_RELAXED,
                                         __HIP_MEMORY_SCOPE_AGENT);
        const float m = __int_as_float(mi);
        int h = (int)ceilf(m + 1.0f);
        if (h < 1) h = 1;
        if (h > 8) h = 8;                      // sigma cap 6 -> h <= 8 always
        s_half = h;
    }
    __syncthreads();
    const int half  = s_half;
    const int k     = 2*half + 1;
    const int tilew = PS + 2*half;             // <= 32
    const int tx = t & 15, ty = t >> 4;

    for (int i = 0; i < 4; ++i) {
        const int p  = blk*4 + i;
        const int bb = p / N_TOK, n = p % N_TOK;
        const int py = n / HP, px = n % HP;
        const float sx = s_sig[i][0], sy = s_sig[i][1], sr = s_sig[i][2];
        const float* xb = x + bb*IMG*IMG;

        for (int yy = ty; yy < tilew; yy += 16) {
            const int gy = py*PS + yy - half;
            for (int xx = tx; xx < tilew; xx += 16) {
                const int gx = px*PS + xx - half;
                float v = 0.f;                 // zero padding, incl. in sums
                if ((unsigned)gy < IMG && (unsigned)gx < IMG)
                    v = xb[gy*IMG + gx];
                tile[yy*40 + xx] = v;
            }
        }
        {
            const float axc = -0.5f/(sx*sx);
            const float ayc = -0.5f/(sy*sy);
            for (int ii = t; ii < k*k; ii += 256) {
                const int dy = ii / k, dx = ii - dy*k;
                const float fy = (float)(dy - half), fx = (float)(dx - half);
                spt[ii] = __expf(ayc*fy*fy + axc*fx*fx);
            }
        }
        __syncthreads();

        const float c   = tile[(ty+half)*40 + (tx+half)];
        const float ar2 = -0.72134752044448170f/(sr*sr);  // -0.5*log2(e)/sr^2
        float num = 0.f, den = 0.f;
        for (int dy = 0; dy < k; ++dy) {
            const float* row = &tile[(ty+dy)*40 + tx];
            const float* spr = &spt[dy*k];     // lane-uniform -> broadcast
            for (int dx = 0; dx < k; ++dx) {
                const float pix = row[dx];
                const float d   = c - pix;
                const float wgt = spr[dx] * exp2f(ar2*d*d);
                den += wgt;
                num += wgt*pix;
            }
        }
        out[bb*IMG*IMG + (py*PS + ty)*IMG + (px*PS + tx)] = num/(den + 1e-8f);
        __syncthreads();                       // WAR before next i reuses tile
    }
}

// ---------------- launch: tiny ctl memset + ONE kernel ---------------------
extern "C" void kernel_launch(void* const* d_in, const int* in_sizes, int n_in,
                              void* d_out, int out_size, void* d_ws, size_t ws_size,
                              hipStream_t stream)
{
    const float* x    = (const float*)d_in[0];
    const float* Wq   = (const float*)d_in[1];
    const float* bq   = (const float*)d_in[2];
    const float* Wk   = (const float*)d_in[3];
    const float* bk   = (const float*)d_in[4];
    const float* Wv   = (const float*)d_in[5];
    const float* bv   = (const float*)d_in[6];
    const float* Wsq  = (const float*)d_in[7];
    const float* bsq  = (const float*)d_in[8];
    const float* Wsk  = (const float*)d_in[9];
    const float* bsk  = (const float*)d_in[10];
    const float* Wsv  = (const float*)d_in[11];
    const float* bsv  = (const float*)d_in[12];
    const float* ln_g = (const float*)d_in[13];
    const float* ln_b = (const float*)d_in[14];
    const float* Wp   = (const float*)d_in[15];
    const float* bp   = (const float*)d_in[16];

    float* W  = (float*)d_ws;
    float* k1 = W;            // 2*576*8 = 9216 floats each
    float* v1 = W +  9216;
    float* k2 = W + 18432;
    float* v2 = W + 27648;
    unsigned* ctl = (unsigned*)(W + 36864);   // 3*132 barrier words + smax

    hipMemsetAsync(ctl, 0, (3*BAR_STRIDE + 1)*sizeof(unsigned), stream);

    k_all<<<NBLK, 256, 0, stream>>>(x, Wq, bq, Wk, bk, Wv, bv,
                                    Wsq, bsq, Wsk, bsk, Wsv, bsv,
                                    ln_g, ln_b, Wp, bp,
                                    k1, v1, k2, v2, ctl, (float*)d_out);
}

// Round 8
// 140.922 us; speedup vs baseline: 1.2778x; 1.2778x over previous
//
#include <hip/hip_runtime.h>

#define N_TOK 576          // 24*24 patches per image
#define HP    24
#define PS    16
#define IMG   384
#define ATTN_SCALE 0.35355339059327373f   // 8^-0.5

// Structure note (rounds 2-7 evidence): every cross-phase dependency here is
// global (attn over all 576 tokens, k from global sigma max), so the pipeline
// needs exactly 3 synchronization points. Measured on MI355X:
//   dispatch boundary ~8-10us < tree-barrier ~20us < coop grid.sync ~65us
// => 4 wide dispatches is the winning structure. Phases must stay wide
// (hundreds of blocks); any narrow fused variant is 10-100x under-parallel.

// ---------------- K1: patchify + first QKV projection (256 -> 8, x3) -------
// One WAVE per patch (4 patches/block). Lane l owns feature indices
// 4l..4l+3 (= pixel row l>>2, cols (l&3)*4 + j) -> float4 coalesced load,
// and reads Wq/Wk/Wv rows 4l..4l+3 = 128 contiguous bytes per lane.
__global__ __launch_bounds__(256) void k_qkv1(
    const float* __restrict__ x,
    const float* __restrict__ Wq, const float* __restrict__ bq,
    const float* __restrict__ Wk, const float* __restrict__ bk,
    const float* __restrict__ Wv, const float* __restrict__ bv,
    float* __restrict__ q1, float* __restrict__ k1, float* __restrict__ v1,
    int* __restrict__ smax)
{
    const int lane = threadIdx.x & 63, wv = threadIdx.x >> 6;
    const int idx = blockIdx.x*4 + wv;        // 0..1151 = b*576 + n
    const int b = idx / N_TOK, n = idx % N_TOK;
    const int py = n / HP, px = n % HP;

    // init smax for k_attn2's atomicMax (plain store: the two dispatch
    // boundaries between here and its readers carry implicit agent
    // acquire/release, so no atomic needed)
    if (idx == 0 && lane == 0) *smax = 0;

    const int iy = lane >> 2, ix0 = (lane & 3) * 4;
    const float4 pv = *(const float4*)
        &x[b*IMG*IMG + (py*PS + iy)*IMG + px*PS + ix0];

    float acc[24];
#pragma unroll
    for (int j = 0; j < 24; ++j) acc[j] = 0.f;

#pragma unroll
    for (int j = 0; j < 4; ++j) {
        const int t = 4*lane + j;             // feature index, row of W
        const float p = ((const float*)&pv)[j];
#pragma unroll
        for (int h = 0; h < 8; ++h) {
            acc[h]      += p * Wq[t*8 + h];
            acc[8 + h]  += p * Wk[t*8 + h];
            acc[16 + h] += p * Wv[t*8 + h];
        }
    }
#pragma unroll
    for (int off = 32; off; off >>= 1)
#pragma unroll
        for (int j = 0; j < 24; ++j) acc[j] += __shfl_xor(acc[j], off);

    if (lane == 0) {
#pragma unroll
        for (int h = 0; h < 8; ++h) {
            q1[idx*8 + h] = acc[h]      + bq[h];
            k1[idx*8 + h] = acc[8 + h]  + bk[h];
            v1[idx*8 + h] = acc[16 + h] + bv[h];
        }
    }
}

// ---------------- K2: attention 1 + fused QKV2 projection ------------------
// one wave per token; 576 keys = 9 chunks of 64; K/V rows loaded as float4x2
__global__ __launch_bounds__(256) void k_attn1(
    const float* __restrict__ q1, const float* __restrict__ k1, const float* __restrict__ v1,
    const float* __restrict__ Wsq, const float* __restrict__ bsq,
    const float* __restrict__ Wsk, const float* __restrict__ bsk,
    const float* __restrict__ Wsv, const float* __restrict__ bsv,
    float* __restrict__ q2, float* __restrict__ k2, float* __restrict__ v2)
{
    const int lane = threadIdx.x & 63;
    const int wv   = threadIdx.x >> 6;
    const int tok  = blockIdx.x*4 + wv;     // 0..1151
    const int b    = tok / N_TOK;

    const float4 qa = *(const float4*)&q1[tok*8];
    const float4 qb = *(const float4*)&q1[tok*8 + 4];

    const float* kbp = k1 + b*N_TOK*8;
    const float* vbp = v1 + b*N_TOK*8;

    float sc[9], mx = -1e30f;
#pragma unroll
    for (int ch = 0; ch < 9; ++ch) {
        const float4* kp = (const float4*)(kbp + (ch*64 + lane)*8);
        const float4 k0 = kp[0], k1v = kp[1];
        float d = qa.x*k0.x + qa.y*k0.y + qa.z*k0.z + qa.w*k0.w
                + qb.x*k1v.x + qb.y*k1v.y + qb.z*k1v.z + qb.w*k1v.w;
        d *= ATTN_SCALE;
        sc[ch] = d;
        mx = fmaxf(mx, d);
    }
#pragma unroll
    for (int off = 32; off; off >>= 1) mx = fmaxf(mx, __shfl_xor(mx, off));

    float ssum = 0.f, o[8];
#pragma unroll
    for (int h = 0; h < 8; ++h) o[h] = 0.f;
#pragma unroll
    for (int ch = 0; ch < 9; ++ch) {
        const float p = __expf(sc[ch] - mx);
        ssum += p;
        const float4* vp = (const float4*)(vbp + (ch*64 + lane)*8);
        const float4 v0 = vp[0], v1v = vp[1];
        o[0] += p*v0.x; o[1] += p*v0.y; o[2] += p*v0.z; o[3] += p*v0.w;
        o[4] += p*v1v.x; o[5] += p*v1v.y; o[6] += p*v1v.z; o[7] += p*v1v.w;
    }
#pragma unroll
    for (int off = 32; off; off >>= 1) {
        ssum += __shfl_xor(ssum, off);
#pragma unroll
        for (int h = 0; h < 8; ++h) o[h] += __shfl_xor(o[h], off);
    }
    const float inv = 1.f/ssum;
    float f[8];
#pragma unroll
    for (int h = 0; h < 8; ++h) f[h] = o[h]*inv;

    if (lane < 24) {
        const int mat = lane >> 3, h = lane & 7;
        const float* Wm = (mat==0)?Wsq:(mat==1)?Wsk:Wsv;
        const float* bm = (mat==0)?bsq:(mat==1)?bsk:bsv;
        float s = bm[h];
#pragma unroll
        for (int j = 0; j < 8; ++j) s += f[j]*Wm[j*8 + h];
        float* dst = (mat==0)?q2:(mat==1)?k2:v2;
        dst[tok*8 + h] = s;
    }
}

// ---------------- K3: attention 2 + LayerNorm + BoundedSoftplus sigmas -----
__global__ __launch_bounds__(256) void k_attn2(
    const float* __restrict__ q2, const float* __restrict__ k2, const float* __restrict__ v2,
    const float* __restrict__ ln_g, const float* __restrict__ ln_b,
    const float* __restrict__ Wp,   const float* __restrict__ bp,
    float* __restrict__ sig, int* __restrict__ smax)
{
    const int lane = threadIdx.x & 63;
    const int wv   = threadIdx.x >> 6;
    const int tok  = blockIdx.x*4 + wv;
    const int b    = tok / N_TOK;

    const float4 qa = *(const float4*)&q2[tok*8];
    const float4 qb = *(const float4*)&q2[tok*8 + 4];

    const float* kbp = k2 + b*N_TOK*8;
    const float* vbp = v2 + b*N_TOK*8;

    float sc[9], mx = -1e30f;
#pragma unroll
    for (int ch = 0; ch < 9; ++ch) {
        const float4* kp = (const float4*)(kbp + (ch*64 + lane)*8);
        const float4 k0 = kp[0], k1v = kp[1];
        float d = qa.x*k0.x + qa.y*k0.y + qa.z*k0.z + qa.w*k0.w
                + qb.x*k1v.x + qb.y*k1v.y + qb.z*k1v.z + qb.w*k1v.w;
        d *= ATTN_SCALE;
        sc[ch] = d;
        mx = fmaxf(mx, d);
    }
#pragma unroll
    for (int off = 32; off; off >>= 1) mx = fmaxf(mx, __shfl_xor(mx, off));

    float ssum = 0.f, o[8];
#pragma unroll
    for (int h = 0; h < 8; ++h) o[h] = 0.f;
#pragma unroll
    for (int ch = 0; ch < 9; ++ch) {
        const float p = __expf(sc[ch] - mx);
        ssum += p;
        const float4* vp = (const float4*)(vbp + (ch*64 + lane)*8);
        const float4 v0 = vp[0], v1v = vp[1];
        o[0] += p*v0.x; o[1] += p*v0.y; o[2] += p*v0.z; o[3] += p*v0.w;
        o[4] += p*v1v.x; o[5] += p*v1v.y; o[6] += p*v1v.z; o[7] += p*v1v.w;
    }
#pragma unroll
    for (int off = 32; off; off >>= 1) {
        ssum += __shfl_xor(ssum, off);
#pragma unroll
        for (int h = 0; h < 8; ++h) o[h] += __shfl_xor(o[h], off);
    }

    if (lane == 0) {
        const float inv = 1.f/ssum;
        float f[8];
        float mu = 0.f;
#pragma unroll
        for (int h = 0; h < 8; ++h) { f[h] = o[h]*inv; mu += f[h]; }
        mu *= 0.125f;
        float var = 0.f;
#pragma unroll
        for (int h = 0; h < 8; ++h) { const float d = f[h]-mu; var += d*d; }
        var *= 0.125f;
        const float rinv = rsqrtf(var + 1e-5f);
        float on[8];
#pragma unroll
        for (int h = 0; h < 8; ++h)
            on[h] = (f[h]-mu)*rinv*ln_g[h] + ln_b[h];
        float sv[3];
#pragma unroll
        for (int c = 0; c < 3; ++c) {
            float z = bp[c];
#pragma unroll
            for (int j = 0; j < 8; ++j) z += on[j]*Wp[j*3 + c];
            const float sp = (z > 20.f) ? z : log1pf(__expf(z));
            sv[c] = fminf(sp, 6.0f) + 1e-6f;
            sig[tok*3 + c] = sv[c];
        }
        atomicMax(smax, __float_as_int(fmaxf(sv[0], sv[1])));
    }
}

// ---------------- K4: bilateral filter (k_half folded in) ------------------
// one block per 16x16 patch; sigmas uniform within a patch.
// LDS tile stride 40 -> only the free 2-way (64 lanes / 32 banks) aliasing.
// Spatial weights precomputed once into LDS (k*k <= 289); range kernel via
// single exp2 with folded -0.5*log2(e)/sr^2 coefficient.
// smax is PLAIN-loaded: the k_attn2->k_bilat dispatch boundary carries an
// implicit agent acquire/release, so no atomic RMW (1152 same-line RMWs
// serialized at the LLC) is needed here.
__global__ __launch_bounds__(256) void k_bilat(
    const float* __restrict__ x, const float* __restrict__ sig,
    const int* __restrict__ smax, float* __restrict__ out)
{
    __shared__ float tile[32*40];
    __shared__ float spt[17*17];
    __shared__ int   s_half;

    const int blk = blockIdx.x;           // b*576 + n
    const int b  = blk / N_TOK;
    const int n  = blk % N_TOK;
    const int py = n / HP, px = n % HP;
    const int tx = threadIdx.x & 15, ty = threadIdx.x >> 4;

    if (threadIdx.x == 0) {
        const float m = __int_as_float(*smax);
        int h = (int)ceilf(m + 1.0f);
        if (h < 1) h = 1;
        if (h > 8) h = 8;                 // sigma cap 6 -> h <= 8 always
        s_half = h;
    }
    __syncthreads();
    const int half = s_half;
    const int k = 2*half + 1;
    const int tilew = PS + 2*half;        // <= 32

    const float sx = sig[blk*3 + 0];
    const float sy = sig[blk*3 + 1];
    const float sr = sig[blk*3 + 2];

    const float* xb = x + b*IMG*IMG;
    for (int yy = ty; yy < tilew; yy += 16) {
        const int gy = py*PS + yy - half;
        for (int xx = tx; xx < tilew; xx += 16) {
            const int gx = px*PS + xx - half;
            float v = 0.f;                // zero padding, included in sums
            if ((unsigned)gy < IMG && (unsigned)gx < IMG)
                v = xb[gy*IMG + gx];
            tile[yy*40 + xx] = v;
        }
    }
    {
        const float axc = -0.5f/(sx*sx);
        const float ayc = -0.5f/(sy*sy);
        for (int i = threadIdx.x; i < k*k; i += 256) {
            const int dy = i / k, dx = i - dy*k;
            const float fy = (float)(dy - half), fx = (float)(dx - half);
            spt[i] = __expf(ayc*fy*fy + axc*fx*fx);
        }
    }
    __syncthreads();

    const float c   = tile[(ty+half)*40 + (tx+half)];
    const float ar2 = -0.72134752044448170f/(sr*sr);   // -0.5*log2(e)/sr^2

    float num = 0.f, den = 0.f;
    for (int dy = 0; dy < k; ++dy) {
        const float* row = &tile[(ty+dy)*40 + tx];
        const float* spr = &spt[dy*k];    // lane-uniform -> LDS broadcast
        for (int dx = 0; dx < k; ++dx) {
            const float pix = row[dx];
            const float d   = c - pix;
            const float w   = spr[dx] * exp2f(ar2*d*d);
            den += w;
            num += w*pix;
        }
    }
    out[b*IMG*IMG + (py*PS + ty)*IMG + (px*PS + tx)] = num/(den + 1e-8f);
}

// ---------------- launch: 4 dispatches, no memset, no barriers -------------
extern "C" void kernel_launch(void* const* d_in, const int* in_sizes, int n_in,
                              void* d_out, int out_size, void* d_ws, size_t ws_size,
                              hipStream_t stream)
{
    const float* x    = (const float*)d_in[0];
    const float* Wq   = (const float*)d_in[1];
    const float* bq   = (const float*)d_in[2];
    const float* Wk   = (const float*)d_in[3];
    const float* bk   = (const float*)d_in[4];
    const float* Wv   = (const float*)d_in[5];
    const float* bv   = (const float*)d_in[6];
    const float* Wsq  = (const float*)d_in[7];
    const float* bsq  = (const float*)d_in[8];
    const float* Wsk  = (const float*)d_in[9];
    const float* bsk  = (const float*)d_in[10];
    const float* Wsv  = (const float*)d_in[11];
    const float* bsv  = (const float*)d_in[12];
    const float* ln_g = (const float*)d_in[13];
    const float* ln_b = (const float*)d_in[14];
    const float* Wp   = (const float*)d_in[15];
    const float* bp   = (const float*)d_in[16];

    float* W  = (float*)d_ws;
    float* q1 = W;            // 2*576*8 = 9216 floats each
    float* k1 = W +  9216;
    float* v1 = W + 18432;
    float* q2 = W + 27648;
    float* k2 = W + 36864;
    float* v2 = W + 46080;
    float* sg = W + 55296;    // 2*576*3 = 3456
    int* smax = (int*)(W + 58752);

    k_qkv1<<<2*N_TOK/4, 256, 0, stream>>>(x, Wq, bq, Wk, bk, Wv, bv,
                                          q1, k1, v1, smax);
    k_attn1<<<2*N_TOK/4, 256, 0, stream>>>(q1, k1, v1, Wsq, bsq, Wsk, bsk,
                                           Wsv, bsv, q2, k2, v2);
    k_attn2<<<2*N_TOK/4, 256, 0, stream>>>(q2, k2, v2, ln_g, ln_b, Wp, bp,
                                           sg, smax);
    k_bilat<<<2*N_TOK, 256, 0, stream>>>(x, sg, smax, (float*)d_out);
}